// Round 6
// baseline (1730.987 us; speedup 1.0000x reference)
//
#include <hip/hip_runtime.h>
#include <cmath>

#define N_NODES 100000
#define N_EDGES 3200000
#define IN_DIM 256
#define EMB 64
#define BATCH 4096
#define MWAVES 6250        // 100000 rows / 16 per wave (gemm)
#define NBUCK 782          // ceil(100000 / 128) row-buckets
#define BROWS 128          // rows per bucket
#define BSTRIDE 4608       // u64 slots per bucket (mean 4096 + 8 sigma)
#define EPB 4096           // edges per passA block

typedef unsigned long long u64;
typedef unsigned int u32;
typedef unsigned short u16;
typedef __attribute__((ext_vector_type(8))) short bf16x8;
typedef __attribute__((ext_vector_type(4))) float f32x4;

// ---------------------------------------------------------------------------
// helpers
// ---------------------------------------------------------------------------
__device__ __forceinline__ float wave_sum(float v) {
#pragma unroll
    for (int m = 1; m < 64; m <<= 1) v += __shfl_xor(v, m, 64);
    return v;
}

__device__ __forceinline__ u16 f2bf_rne(float f) {
    u32 u = __float_as_uint(f);
    u32 r = ((u >> 16) & 1u) + 0x7FFFu;
    return (u16)((u + r) >> 16);
}

__device__ __forceinline__ float bf2f(u32 bits16) {
    return __uint_as_float(bits16 << 16);
}

__device__ __forceinline__ u64 shfl64(u64 v, int src) {
    int lo = __shfl((int)(u32)v, src, 64);
    int hi = __shfl((int)(v >> 32), src, 64);
    return ((u64)(u32)hi << 32) | (u32)lo;
}

// ---------------------------------------------------------------------------
// 1) xw = feats @ W via MFMA bf16. W staged in LDS fragment-major (32 KB).
// ---------------------------------------------------------------------------
__global__ __launch_bounds__(256) void mfma_gemm_kernel(const float* __restrict__ feats,
                                                        const float* __restrict__ W,
                                                        u16* __restrict__ xwb) {
    __shared__ u16 wlds[32 * 64 * 8];   // 32 KB
    const int tid = threadIdx.x;
    for (int idx = tid; idx < 32 * 64; idx += 256) {
        const int f = idx >> 6, lane = idx & 63;
        const int kt = f >> 2, nt = f & 3;
        const int k0 = kt * 32 + (lane >> 4) * 8;
        const int n  = nt * 16 + (lane & 15);
        u32 buf[4];
#pragma unroll
        for (int jj = 0; jj < 4; ++jj) {
            u16 lo = f2bf_rne(W[(size_t)(k0 + 2 * jj) * EMB + n]);
            u16 hi = f2bf_rne(W[(size_t)(k0 + 2 * jj + 1) * EMB + n]);
            buf[jj] = (u32)lo | ((u32)hi << 16);
        }
        *(uint4*)&wlds[idx * 8] = *(uint4*)buf;
    }
    __syncthreads();

    const int wave = tid >> 6, lane = tid & 63;
    const int wid = blockIdx.x * 4 + wave;
    if (wid >= MWAVES) return;
    const int row0 = wid * 16;
    const int arow = row0 + (lane & 15);
    const int kbase = (lane >> 4) * 8;

    f32x4 acc[4] = {};
    const u16* wl = &wlds[lane * 8];
#pragma unroll
    for (int kt = 0; kt < 8; ++kt) {
        const float* ap = feats + (size_t)arow * IN_DIM + kt * 32 + kbase;
        float4 a0 = *(const float4*)ap;
        float4 a1 = *(const float4*)(ap + 4);
        u32 ab[4];
        ab[0] = (u32)f2bf_rne(a0.x) | ((u32)f2bf_rne(a0.y) << 16);
        ab[1] = (u32)f2bf_rne(a0.z) | ((u32)f2bf_rne(a0.w) << 16);
        ab[2] = (u32)f2bf_rne(a1.x) | ((u32)f2bf_rne(a1.y) << 16);
        ab[3] = (u32)f2bf_rne(a1.z) | ((u32)f2bf_rne(a1.w) << 16);
        bf16x8 afrag = *(bf16x8*)ab;
#pragma unroll
        for (int nt = 0; nt < 4; ++nt) {
            bf16x8 bfrag = *(const bf16x8*)&wl[(kt * 4 + nt) * 512];
            acc[nt] = __builtin_amdgcn_mfma_f32_16x16x32_bf16(afrag, bfrag, acc[nt], 0, 0, 0);
        }
    }
    const int rb = row0 + (lane >> 4) * 4;
    const int cb = lane & 15;
#pragma unroll
    for (int nt = 0; nt < 4; ++nt)
#pragma unroll
        for (int r = 0; r < 4; ++r)
            xwb[(size_t)(rb + r) * EMB + nt * 16 + cb] = f2bf_rne(acc[nt][r]);
}

// ---------------------------------------------------------------------------
// 2) passA: partition edges into NBUCK row-buckets.
//    Per block: LDS hist -> LDS scan -> LDS counting-sort stage -> one global
//    atomicAdd per (block,bucket) -> coalesced burst write of bucket runs.
//    Entry packs (row:17 | col:17<<17 | val_bf16<<34).
// ---------------------------------------------------------------------------
__global__ __launch_bounds__(256) void passA_kernel(const int* __restrict__ erow,
                                                    const int* __restrict__ ecol,
                                                    const float* __restrict__ eval,
                                                    u32* __restrict__ gcursor,
                                                    u64* __restrict__ sorted) {
    __shared__ u64 stage[EPB];        // 32 KB
    __shared__ u32 hist[1024];        // padded (NBUCK=782)
    __shared__ u32 offs[1024];
    __shared__ u32 cursor[1024];
    __shared__ u32 gbase[1024];
    __shared__ u32 partial[256];

    const int tid = threadIdx.x;
    const int e0 = blockIdx.x * EPB;
    const int total = min(EPB, N_EDGES - e0);

    for (int i = tid; i < 1024; i += 256) hist[i] = 0;
    __syncthreads();

    // read 16 edges/thread, histogram buckets
    u64 ent[16];
    int eb[16];
#pragma unroll
    for (int j = 0; j < 16; ++j) {
        const int e = e0 + j * 256 + tid;
        if (e < N_EDGES) {
            const int r = erow[e];
            const int c = ecol[e];
            const u16 vb = f2bf_rne(eval[e]);
            ent[j] = (u64)(u32)r | ((u64)(u32)c << 17) | ((u64)vb << 34);
            eb[j] = r >> 7;
            atomicAdd(&hist[eb[j]], 1u);
        } else {
            eb[j] = -1;
        }
    }
    __syncthreads();

    // exclusive scan of hist[1024]: 4 slots/thread + Hillis-Steele on partials
    u32 local[4], s = 0;
#pragma unroll
    for (int q = 0; q < 4; ++q) {
        local[q] = s;
        s += hist[4 * tid + q];
    }
    partial[tid] = s;
    __syncthreads();
    for (int off = 1; off < 256; off <<= 1) {
        u32 x = (tid >= off) ? partial[tid - off] : 0;
        __syncthreads();
        partial[tid] += x;
        __syncthreads();
    }
    const u32 base = partial[tid] - s;   // exclusive
#pragma unroll
    for (int q = 0; q < 4; ++q) {
        offs[4 * tid + q] = base + local[q];
        cursor[4 * tid + q] = base + local[q];
    }
    __syncthreads();

    // counting-sort into LDS stage
#pragma unroll
    for (int j = 0; j < 16; ++j) {
        if (eb[j] >= 0) {
            u32 pos = atomicAdd(&cursor[eb[j]], 1u);
            stage[pos] = ent[j];
        }
    }
    __syncthreads();

    // reserve global space: one atomicAdd per non-empty bucket
    for (int b = tid; b < 1024; b += 256) {
        const u32 cnt = cursor[b] - offs[b];
        gbase[b] = cnt ? atomicAdd(&gcursor[b], cnt) : 0;
    }
    __syncthreads();

    // coalesced write-out of bucket runs
    for (int i = tid; i < total; i += 256) {
        const u64 p = stage[i];
        const int b = (int)(p & 0x1FFFFu) >> 7;
        const u32 gpos = gbase[b] + ((u32)i - offs[b]);
        if (gpos < BSTRIDE) sorted[(size_t)b * BSTRIDE + gpos] = p;
    }
}

// ---------------------------------------------------------------------------
// 3) passB: one block per bucket. f32 LDS tile 128x64; stream bucket entries
//    sequentially; per edge: coalesced xw-row gather + ds_add_f32 into tile.
//    Epilogue: tanh + normalize; emb rows (bf16) stored over the bucket's own
//    dead entry region; weight-decay term accumulated.
// ---------------------------------------------------------------------------
__global__ __launch_bounds__(256) void passB_kernel(const u16* __restrict__ xwb,
                                                    u64* __restrict__ sorted,
                                                    const u32* __restrict__ gcursor,
                                                    float* __restrict__ accumA) {
    __shared__ float tile[BROWS * EMB];   // 32 KB
    const int tid = threadIdx.x;
    const int wave = tid >> 6, lane = tid & 63;
    const int b = blockIdx.x;

    float4* t4 = (float4*)tile;
    for (int i = tid; i < BROWS * EMB / 4; i += 256) t4[i] = make_float4(0.f, 0.f, 0.f, 0.f);
    __syncthreads();

    const u64* ents = sorted + (size_t)b * BSTRIDE;
    const int cnt = min((int)gcursor[b], BSTRIDE);

    for (int bi = wave * 64; bi < cnt; bi += 256) {
        const int k = min(64, cnt - bi);
        u64 myent = (lane < k) ? ents[bi + lane] : 0;
        int j = 0;
        for (; j + 3 < k; j += 4) {
            u64 p0 = shfl64(myent, j);
            u64 p1 = shfl64(myent, j + 1);
            u64 p2 = shfl64(myent, j + 2);
            u64 p3 = shfl64(myent, j + 3);
            float x0 = bf2f(xwb[(size_t)((p0 >> 17) & 0x1FFFFu) * EMB + lane]);
            float x1 = bf2f(xwb[(size_t)((p1 >> 17) & 0x1FFFFu) * EMB + lane]);
            float x2 = bf2f(xwb[(size_t)((p2 >> 17) & 0x1FFFFu) * EMB + lane]);
            float x3 = bf2f(xwb[(size_t)((p3 >> 17) & 0x1FFFFu) * EMB + lane]);
            atomicAdd(&tile[((int)(p0 & 0x1FFFFu) & 127) * EMB + lane], bf2f((u32)(p0 >> 34) & 0xFFFFu) * x0);
            atomicAdd(&tile[((int)(p1 & 0x1FFFFu) & 127) * EMB + lane], bf2f((u32)(p1 >> 34) & 0xFFFFu) * x1);
            atomicAdd(&tile[((int)(p2 & 0x1FFFFu) & 127) * EMB + lane], bf2f((u32)(p2 >> 34) & 0xFFFFu) * x2);
            atomicAdd(&tile[((int)(p3 & 0x1FFFFu) & 127) * EMB + lane], bf2f((u32)(p3 >> 34) & 0xFFFFu) * x3);
        }
        for (; j < k; ++j) {
            u64 p = shfl64(myent, j);
            float x = bf2f(xwb[(size_t)((p >> 17) & 0x1FFFFu) * EMB + lane]);
            atomicAdd(&tile[((int)(p & 0x1FFFFu) & 127) * EMB + lane], bf2f((u32)(p >> 34) & 0xFFFFu) * x);
        }
    }
    __syncthreads();

    // epilogue: rows wave*32 .. wave*32+31; emb overlays this bucket's entries
    u16* embp = (u16*)(sorted + (size_t)b * BSTRIDE);
    float part = 0.f;
    for (int lr = wave * 32; lr < wave * 32 + 32; ++lr) {
        float x = tanhf(tile[lr * EMB + lane]);
        float sq = wave_sum(x * x);
        float inv = rsqrtf(fmaxf(sq, 1e-12f));
        embp[lr * EMB + lane] = f2bf_rne(x * inv);
        part += sq / fmaxf(sq, 1e-12f);      // sum(emb^2) of row (0 if empty)
    }
    if (lane == 0) unsafeAtomicAdd(&accumA[(b * 4 + wave) & 255], part);
}

// ---------------------------------------------------------------------------
// 4) BPR: pure emb lookup. One wave per sample.
// ---------------------------------------------------------------------------
__device__ __forceinline__ float emb_ld(const u64* __restrict__ sorted, int row, int lane) {
    const u16* rp = (const u16*)(sorted + (size_t)(row >> 7) * BSTRIDE) + (row & 127) * EMB;
    return bf2f(rp[lane]);
}

__global__ __launch_bounds__(256) void bpr_kernel(const u64* __restrict__ sorted,
                                                  const int* __restrict__ idx1,
                                                  const int* __restrict__ idx2,
                                                  const int* __restrict__ nidx,
                                                  float* __restrict__ accumB) {
    const int wave = threadIdx.x >> 6, lane = threadIdx.x & 63;
    const int i = blockIdx.x * 4 + wave;       // 1024*4 == BATCH exact
    float o1 = emb_ld(sorted, idx1[i], lane);
    float o2 = emb_ld(sorted, idx2[i], lane);
    float on = emb_ld(sorted, nidx[i], lane);
    float yui = wave_sum(o1 * o2);
    float yuj = wave_sum(o1 * on);
    if (lane == 0) {
        float x = yui - yuj;
        float li = (x > 0.f) ? log1pf(expf(-x)) : (-x + log1pf(expf(x)));
        unsafeAtomicAdd(&accumB[i & 255], li);
    }
}

// ---------------------------------------------------------------------------
// 5) finalize
// ---------------------------------------------------------------------------
__global__ __launch_bounds__(64) void finalize_kernel(const float* __restrict__ accumA,
                                                      const float* __restrict__ accumB,
                                                      float* __restrict__ out) {
    const int t = threadIdx.x;
    float wd = 0.f, bp = 0.f;
#pragma unroll
    for (int k = 0; k < 4; ++k) {
        wd += accumA[t + 64 * k];
        bp += accumB[t + 64 * k];
    }
    wd = wave_sum(wd);
    bp = wave_sum(bp);
    if (t == 0) out[0] = (bp + 1e-4f * 0.5f * wd) / (float)BATCH;
}

extern "C" void kernel_launch(void* const* d_in, const int* in_sizes, int n_in,
                              void* d_out, int out_size, void* d_ws, size_t ws_size,
                              hipStream_t stream) {
    const float* feats = (const float*)d_in[0];
    const float* W     = (const float*)d_in[1];
    const int*   erow  = (const int*)d_in[2];
    const int*   ecol  = (const int*)d_in[3];
    const float* eval  = (const float*)d_in[4];
    const int*   idx1  = (const int*)d_in[5];
    const int*   idx2  = (const int*)d_in[6];
    const int*   nidx  = (const int*)d_in[7];
    float* out = (float*)d_out;

    // workspace layout (~41.7 MB)
    u16*   xwb     = (u16*)d_ws;                             // 6.4M u16 = 12.8 MB
    u64*   sorted  = (u64*)(xwb + (size_t)N_NODES * EMB);    // 782*4608 u64 = 28.8 MB
    u32*   gcursor = (u32*)(sorted + (size_t)NBUCK * BSTRIDE); // 1024 u32
    float* accumA  = (float*)(gcursor + 1024);               // 256
    float* accumB  = accumA + 256;                           // 256

    hipMemsetAsync(gcursor, 0, (1024 + 512) * sizeof(u32), stream);

    mfma_gemm_kernel<<<(MWAVES + 3) / 4, 256, 0, stream>>>(feats, W, xwb);
    passA_kernel<<<(N_EDGES + EPB - 1) / EPB, 256, 0, stream>>>(erow, ecol, eval, gcursor, sorted);
    passB_kernel<<<NBUCK, 256, 0, stream>>>(xwb, sorted, gcursor, accumA);
    bpr_kernel<<<BATCH / 4, 256, 0, stream>>>(sorted, idx1, idx2, nidx, accumB);
    finalize_kernel<<<1, 64, 0, stream>>>(accumA, accumB, out);
}

// Round 7
// 353.178 us; speedup vs baseline: 4.9012x; 4.9012x over previous
//
#include <hip/hip_runtime.h>
#include <cmath>

#define N_NODES 100000
#define N_EDGES 3200000
#define IN_DIM 256
#define EMB 64
#define BATCH 4096
#define MWAVES 6250        // 100000 rows / 16 per wave (gemm)
#define NBUCK 782          // ceil(100000 / 128) row-buckets
#define BROWS 128          // rows per bucket
#define BSTRIDE 4608       // u64 slots per bucket (mean 4096 + 8 sigma), %8==0
#define SUBS 8             // sub-buckets per bucket (16 rows each)
#define NSUB (NBUCK * SUBS)
#define CAPSUB 768         // LDS stage capacity per sub-run (mean 512, sigma 23)
#define EPB 4096           // edges per passA block

typedef unsigned long long u64;
typedef unsigned int u32;
typedef unsigned short u16;
typedef __attribute__((ext_vector_type(8))) short bf16x8;
typedef __attribute__((ext_vector_type(4))) float f32x4;

// ---------------------------------------------------------------------------
// helpers
// ---------------------------------------------------------------------------
__device__ __forceinline__ float wave_sum(float v) {
#pragma unroll
    for (int m = 1; m < 64; m <<= 1) v += __shfl_xor(v, m, 64);
    return v;
}

__device__ __forceinline__ u16 f2bf_rne(float f) {
    u32 u = __float_as_uint(f);
    u32 r = ((u >> 16) & 1u) + 0x7FFFu;
    return (u16)((u + r) >> 16);
}

__device__ __forceinline__ float bf2f(u32 bits16) {
    return __uint_as_float(bits16 << 16);
}

// ---------------------------------------------------------------------------
// 1) xw = feats @ W via MFMA bf16. W staged in LDS fragment-major (32 KB).
//    All 16 A-tile float4 loads hoisted before the MFMA loop: ONE latency
//    exposure per wave instead of 8 (R4-R6 had 8 serial HBM round-trips).
// ---------------------------------------------------------------------------
__global__ __launch_bounds__(256) void mfma_gemm_kernel(const float* __restrict__ feats,
                                                        const float* __restrict__ W,
                                                        u16* __restrict__ xwb) {
    __shared__ u16 wlds[32 * 64 * 8];   // 32 KB
    const int tid = threadIdx.x;
    for (int idx = tid; idx < 32 * 64; idx += 256) {
        const int f = idx >> 6, lane = idx & 63;
        const int kt = f >> 2, nt = f & 3;
        const int k0 = kt * 32 + (lane >> 4) * 8;
        const int n  = nt * 16 + (lane & 15);
        u32 buf[4];
#pragma unroll
        for (int jj = 0; jj < 4; ++jj) {
            u16 lo = f2bf_rne(W[(size_t)(k0 + 2 * jj) * EMB + n]);
            u16 hi = f2bf_rne(W[(size_t)(k0 + 2 * jj + 1) * EMB + n]);
            buf[jj] = (u32)lo | ((u32)hi << 16);
        }
        *(uint4*)&wlds[idx * 8] = *(uint4*)buf;
    }
    __syncthreads();

    const int wave = tid >> 6, lane = tid & 63;
    const int wid = blockIdx.x * 4 + wave;
    if (wid >= MWAVES) return;
    const int row0 = wid * 16;
    const int arow = row0 + (lane & 15);
    const int kbase = (lane >> 4) * 8;
    const float* fr = feats + (size_t)arow * IN_DIM + kbase;

    // hoisted A loads: 16 x float4 (64 VGPRs), all in flight together
    float4 av[16];
#pragma unroll
    for (int kt = 0; kt < 8; ++kt) {
        av[2 * kt]     = *(const float4*)(fr + kt * 32);
        av[2 * kt + 1] = *(const float4*)(fr + kt * 32 + 4);
    }

    f32x4 acc[4] = {};
    const u16* wl = &wlds[lane * 8];
#pragma unroll
    for (int kt = 0; kt < 8; ++kt) {
        float4 a0 = av[2 * kt], a1 = av[2 * kt + 1];
        u32 ab[4];
        ab[0] = (u32)f2bf_rne(a0.x) | ((u32)f2bf_rne(a0.y) << 16);
        ab[1] = (u32)f2bf_rne(a0.z) | ((u32)f2bf_rne(a0.w) << 16);
        ab[2] = (u32)f2bf_rne(a1.x) | ((u32)f2bf_rne(a1.y) << 16);
        ab[3] = (u32)f2bf_rne(a1.z) | ((u32)f2bf_rne(a1.w) << 16);
        bf16x8 afrag = *(bf16x8*)ab;
#pragma unroll
        for (int nt = 0; nt < 4; ++nt) {
            bf16x8 bfrag = *(const bf16x8*)&wl[(kt * 4 + nt) * 512];
            acc[nt] = __builtin_amdgcn_mfma_f32_16x16x32_bf16(afrag, bfrag, acc[nt], 0, 0, 0);
        }
    }
    const int rb = row0 + (lane >> 4) * 4;
    const int cb = lane & 15;
#pragma unroll
    for (int nt = 0; nt < 4; ++nt)
#pragma unroll
        for (int r = 0; r < 4; ++r)
            xwb[(size_t)(rb + r) * EMB + nt * 16 + cb] = f2bf_rne(acc[nt][r]);
}

// ---------------------------------------------------------------------------
// 2) passA: partition edges into NBUCK 128-row buckets (R6-proven).
//    Entry packs (row:17 | col:17<<17 | val_bf16<<34).
// ---------------------------------------------------------------------------
__global__ __launch_bounds__(256) void passA_kernel(const int* __restrict__ erow,
                                                    const int* __restrict__ ecol,
                                                    const float* __restrict__ eval,
                                                    u32* __restrict__ gcursor,
                                                    u64* __restrict__ sorted) {
    __shared__ u64 stage[EPB];        // 32 KB
    __shared__ u32 hist[1024];
    __shared__ u32 offs[1024];
    __shared__ u32 cursor[1024];
    __shared__ u32 gbase[1024];
    __shared__ u32 partial[256];

    const int tid = threadIdx.x;
    const int e0 = blockIdx.x * EPB;
    const int total = min(EPB, N_EDGES - e0);

    for (int i = tid; i < 1024; i += 256) hist[i] = 0;
    __syncthreads();

    u64 ent[16];
    int eb[16];
#pragma unroll
    for (int j = 0; j < 16; ++j) {
        const int e = e0 + j * 256 + tid;
        if (e < N_EDGES) {
            const int r = erow[e];
            const int c = ecol[e];
            const u16 vb = f2bf_rne(eval[e]);
            ent[j] = (u64)(u32)r | ((u64)(u32)c << 17) | ((u64)vb << 34);
            eb[j] = r >> 7;
            atomicAdd(&hist[eb[j]], 1u);
        } else {
            eb[j] = -1;
        }
    }
    __syncthreads();

    u32 local[4], s = 0;
#pragma unroll
    for (int q = 0; q < 4; ++q) {
        local[q] = s;
        s += hist[4 * tid + q];
    }
    partial[tid] = s;
    __syncthreads();
    for (int off = 1; off < 256; off <<= 1) {
        u32 x = (tid >= off) ? partial[tid - off] : 0;
        __syncthreads();
        partial[tid] += x;
        __syncthreads();
    }
    const u32 base = partial[tid] - s;
#pragma unroll
    for (int q = 0; q < 4; ++q) {
        offs[4 * tid + q] = base + local[q];
        cursor[4 * tid + q] = base + local[q];
    }
    __syncthreads();

#pragma unroll
    for (int j = 0; j < 16; ++j) {
        if (eb[j] >= 0) {
            u32 pos = atomicAdd(&cursor[eb[j]], 1u);
            stage[pos] = ent[j];
        }
    }
    __syncthreads();

    for (int b = tid; b < 1024; b += 256) {
        const u32 cnt = cursor[b] - offs[b];
        gbase[b] = cnt ? atomicAdd(&gcursor[b], cnt) : 0;
    }
    __syncthreads();

    for (int i = tid; i < total; i += 256) {
        const u64 p = stage[i];
        const int b = (int)(p & 0x1FFFFu) >> 7;
        const u32 gpos = gbase[b] + ((u32)i - offs[b]);
        if (gpos < BSTRIDE) sorted[(size_t)b * BSTRIDE + gpos] = p;
    }
}

// ---------------------------------------------------------------------------
// 2b) passA2: in-place re-sort each bucket into 8 sub-runs of 16 rows,
//     64B-aligned run starts (race-free emb overlay later). Coalesced IO.
// ---------------------------------------------------------------------------
__global__ __launch_bounds__(256) void passA2_kernel(u64* __restrict__ sorted,
                                                     const u32* __restrict__ gcursor,
                                                     u32* __restrict__ subrun,
                                                     u32* __restrict__ subcnt) {
    __shared__ u64 stage[BSTRIDE];        // 36.9 KB
    __shared__ u32 whist[4][SUBS];
    __shared__ u32 wcur[4][SUBS];
    __shared__ u32 sstart[SUBS], scnt[SUBS], send;

    const int tid = threadIdx.x, wave = tid >> 6;
    const int b = blockIdx.x;
    u64* base = sorted + (size_t)b * BSTRIDE;
    const int cnt = min((int)gcursor[b], BSTRIDE);

    if (tid < 32) whist[tid >> 3][tid & 7] = 0;
    __syncthreads();

    // read entries to registers (coalesced), per-wave histograms
    u64 ent[BSTRIDE / 256 + 1];
    int nloc = 0;
    for (int i = tid; i < cnt; i += 256) {
        u64 p = base[i];
        ent[nloc++] = p;
        atomicAdd(&whist[wave][(int)(p >> 4) & 7], 1u);
    }
    __syncthreads();

    if (tid == 0) {
        u32 o = 0;
        for (int s2 = 0; s2 < SUBS; ++s2) {
            u32 t = whist[0][s2] + whist[1][s2] + whist[2][s2] + whist[3][s2];
            u32 st = min(o, (u32)BSTRIDE);
            t = min(t, (u32)BSTRIDE - st);
            sstart[s2] = st;
            scnt[s2] = t;
            o = (st + t + 7) & ~7u;       // 64B-align next run
        }
        send = min(o, (u32)BSTRIDE);
    }
    __syncthreads();
    if (tid < 32) {
        const int w = tid >> 3, s2 = tid & 7;
        u32 o = sstart[s2];
        for (int w2 = 0; w2 < w; ++w2) o += whist[w2][s2];
        wcur[w][s2] = o;
    }
    __syncthreads();

    // scatter into LDS at final in-bucket positions
    for (int j = 0; j < nloc; ++j) {
        const u64 p = ent[j];
        const u32 pos = atomicAdd(&wcur[wave][(int)(p >> 4) & 7], 1u);
        if (pos < BSTRIDE) stage[pos] = p;
    }
    __syncthreads();

    // coalesced write-back of the used region (holes harmless, never read)
    const u32 e2 = send;
    for (u32 i = tid; i < e2; i += 256) base[i] = stage[i];
    if (tid < SUBS) {
        subrun[b * SUBS + tid] = (u32)(b * BSTRIDE) + sstart[tid];
        subcnt[b * SUBS + tid] = scnt[tid];
    }
}

// ---------------------------------------------------------------------------
// 3) gather: one block per 16-row sub-run (6256 blocks). LDS-sort run into
//    16 per-row lists; each wave sweeps 4 rows with wave-uniform LDS reads
//    + 8-wide unrolled xw gathers. emb (bf16) overlays own run region.
// ---------------------------------------------------------------------------
__global__ __launch_bounds__(256) void gather_kernel(const u16* __restrict__ xwb,
                                                     u64* __restrict__ sorted,
                                                     const u32* __restrict__ subrun,
                                                     const u32* __restrict__ subcnt,
                                                     float* __restrict__ accumA) {
    __shared__ u64 stage[CAPSUB];     // 6 KB
    __shared__ u32 rhist[16], roff[16], rcur[16];
    __shared__ float part[4];
    const int tid = threadIdx.x, wave = tid >> 6, lane = tid & 63;
    const int blk = blockIdx.x;
    const u32 base = subrun[blk];
    const int cnt = min((int)subcnt[blk], CAPSUB);

    if (tid < 16) rhist[tid] = 0;
    __syncthreads();
    for (int i = tid; i < cnt; i += 256)
        atomicAdd(&rhist[(int)(sorted[base + i] & 0xFu)], 1u);
    __syncthreads();
    if (tid == 0) {
        u32 o = 0;
        for (int r = 0; r < 16; ++r) { roff[r] = o; rcur[r] = o; o += rhist[r]; }
    }
    __syncthreads();
    for (int i = tid; i < cnt; i += 256) {
        const u64 p = sorted[base + i];                 // L2-hot second read
        const u32 pos = atomicAdd(&rcur[(int)(p & 0xFu)], 1u);
        stage[pos] = p;
    }
    __syncthreads();

    u16* embp = (u16*)(sorted + base);
    float wd = 0.f;
#pragma unroll
    for (int rr = 0; rr < 4; ++rr) {
        const int r = wave * 4 + rr;
        const int s0 = roff[r], n = rhist[r];
        float acc = 0.f;
        int j = s0;
        const int e2 = s0 + n;
        for (; j + 7 < e2; j += 8) {
            u64 p0 = stage[j],     p1 = stage[j + 1], p2 = stage[j + 2], p3 = stage[j + 3];
            u64 p4 = stage[j + 4], p5 = stage[j + 5], p6 = stage[j + 6], p7 = stage[j + 7];
            float x0 = bf2f(xwb[(size_t)((p0 >> 17) & 0x1FFFFu) * EMB + lane]);
            float x1 = bf2f(xwb[(size_t)((p1 >> 17) & 0x1FFFFu) * EMB + lane]);
            float x2 = bf2f(xwb[(size_t)((p2 >> 17) & 0x1FFFFu) * EMB + lane]);
            float x3 = bf2f(xwb[(size_t)((p3 >> 17) & 0x1FFFFu) * EMB + lane]);
            float x4 = bf2f(xwb[(size_t)((p4 >> 17) & 0x1FFFFu) * EMB + lane]);
            float x5 = bf2f(xwb[(size_t)((p5 >> 17) & 0x1FFFFu) * EMB + lane]);
            float x6 = bf2f(xwb[(size_t)((p6 >> 17) & 0x1FFFFu) * EMB + lane]);
            float x7 = bf2f(xwb[(size_t)((p7 >> 17) & 0x1FFFFu) * EMB + lane]);
            acc += bf2f((u32)(p0 >> 34) & 0xFFFFu) * x0 + bf2f((u32)(p1 >> 34) & 0xFFFFu) * x1;
            acc += bf2f((u32)(p2 >> 34) & 0xFFFFu) * x2 + bf2f((u32)(p3 >> 34) & 0xFFFFu) * x3;
            acc += bf2f((u32)(p4 >> 34) & 0xFFFFu) * x4 + bf2f((u32)(p5 >> 34) & 0xFFFFu) * x5;
            acc += bf2f((u32)(p6 >> 34) & 0xFFFFu) * x6 + bf2f((u32)(p7 >> 34) & 0xFFFFu) * x7;
        }
        for (; j < e2; ++j) {
            u64 p = stage[j];
            acc += bf2f((u32)(p >> 34) & 0xFFFFu) * bf2f(xwb[(size_t)((p >> 17) & 0x1FFFFu) * EMB + lane]);
        }
        float x = tanhf(acc);
        float sq = wave_sum(x * x);
        if (blk * 16 + r < N_NODES)
            embp[r * EMB + lane] = f2bf_rne(x * rsqrtf(fmaxf(sq, 1e-12f)));
        wd += sq / fmaxf(sq, 1e-12f);
    }
    if (lane == 0) part[wave] = wd;
    __syncthreads();
    if (tid == 0)
        unsafeAtomicAdd(&accumA[blk & 255], part[0] + part[1] + part[2] + part[3]);
}

// ---------------------------------------------------------------------------
// 4) BPR: pure emb lookup via subrun offsets.
// ---------------------------------------------------------------------------
__global__ __launch_bounds__(256) void bpr_kernel(const u64* __restrict__ sorted,
                                                  const u32* __restrict__ subrun,
                                                  const int* __restrict__ idx1,
                                                  const int* __restrict__ idx2,
                                                  const int* __restrict__ nidx,
                                                  float* __restrict__ accumB) {
    const int wave = threadIdx.x >> 6, lane = threadIdx.x & 63;
    const int i = blockIdx.x * 4 + wave;
    const int a = idx1[i], b = idx2[i], n = nidx[i];
    float o1 = bf2f(((const u16*)(sorted + subrun[a >> 4]))[(a & 15) * EMB + lane]);
    float o2 = bf2f(((const u16*)(sorted + subrun[b >> 4]))[(b & 15) * EMB + lane]);
    float on = bf2f(((const u16*)(sorted + subrun[n >> 4]))[(n & 15) * EMB + lane]);
    float yui = wave_sum(o1 * o2);
    float yuj = wave_sum(o1 * on);
    if (lane == 0) {
        float x = yui - yuj;
        float li = (x > 0.f) ? log1pf(expf(-x)) : (-x + log1pf(expf(x)));
        unsafeAtomicAdd(&accumB[i & 255], li);
    }
}

// ---------------------------------------------------------------------------
// 5) finalize
// ---------------------------------------------------------------------------
__global__ __launch_bounds__(64) void finalize_kernel(const float* __restrict__ accumA,
                                                      const float* __restrict__ accumB,
                                                      float* __restrict__ out) {
    const int t = threadIdx.x;
    float wd = 0.f, bp = 0.f;
#pragma unroll
    for (int k = 0; k < 4; ++k) {
        wd += accumA[t + 64 * k];
        bp += accumB[t + 64 * k];
    }
    wd = wave_sum(wd);
    bp = wave_sum(bp);
    if (t == 0) out[0] = (bp + 1e-4f * 0.5f * wd) / (float)BATCH;
}

extern "C" void kernel_launch(void* const* d_in, const int* in_sizes, int n_in,
                              void* d_out, int out_size, void* d_ws, size_t ws_size,
                              hipStream_t stream) {
    const float* feats = (const float*)d_in[0];
    const float* W     = (const float*)d_in[1];
    const int*   erow  = (const int*)d_in[2];
    const int*   ecol  = (const int*)d_in[3];
    const float* eval  = (const float*)d_in[4];
    const int*   idx1  = (const int*)d_in[5];
    const int*   idx2  = (const int*)d_in[6];
    const int*   nidx  = (const int*)d_in[7];
    float* out = (float*)d_out;

    // workspace layout (~41.7 MB)
    u16*   xwb     = (u16*)d_ws;                               // 12.8 MB
    u64*   sorted  = (u64*)(xwb + (size_t)N_NODES * EMB);      // 782*4608*8 = 28.8 MB
    u32*   gcursor = (u32*)(sorted + (size_t)NBUCK * BSTRIDE); // 1024
    u32*   subcnt  = gcursor + 1024;                           // 6272
    u32*   subrun  = subcnt + 6272;                            // 6272
    float* accumA  = (float*)(subrun + 6272);                  // 256
    float* accumB  = accumA + 256;                             // 256

    hipMemsetAsync(gcursor, 0, (1024 + 6272 + 6272 + 512) * sizeof(u32), stream);

    mfma_gemm_kernel<<<(MWAVES + 3) / 4, 256, 0, stream>>>(feats, W, xwb);
    passA_kernel<<<(N_EDGES + EPB - 1) / EPB, 256, 0, stream>>>(erow, ecol, eval, gcursor, sorted);
    passA2_kernel<<<NBUCK, 256, 0, stream>>>(sorted, gcursor, subrun, subcnt);
    gather_kernel<<<NSUB, 256, 0, stream>>>(xwb, sorted, subrun, subcnt, accumA);
    bpr_kernel<<<BATCH / 4, 256, 0, stream>>>(sorted, subrun, idx1, idx2, nidx, accumB);
    finalize_kernel<<<1, 64, 0, stream>>>(accumA, accumB, out);
}